// Round 6
// baseline (190.165 us; speedup 1.0000x reference)
//
#include <hip/hip_runtime.h>
#include <stdint.h>

typedef unsigned short u16;
typedef unsigned int u32;
typedef short v8s __attribute__((ext_vector_type(8)));
typedef float v4f __attribute__((ext_vector_type(4)));

#define N_NODES 8192
#define N_EDGES 524288
#define DFEAT 256
#define PAD 160   // per-receiver bucket capacity; deg ~ Bin(524288, 2^-13): mean 64, sigma 8

typedef __attribute__((address_space(3))) void lds_t;
typedef const __attribute__((address_space(1))) void gbl_t;

static __device__ __forceinline__ float bflo(u32 u) { return __uint_as_float(u << 16); }
static __device__ __forceinline__ float bfhi(u32 u) { return __uint_as_float(u & 0xffff0000u); }
static __device__ __forceinline__ u16 f2bf(float f) {
    u32 u = __float_as_uint(f);
    u32 r = (u + 0x7fffu + ((u >> 16) & 1u)) >> 16;
    return (u16)r;
}

// ---- fused prep: conv h->bf16 | LDS-tiled W transpose->bf16 | padded-bucket scatter ----
__global__ void prep(const float* __restrict__ h,
                     const float* __restrict__ w0, const float* __restrict__ w1,
                     const float* __restrict__ w2,
                     const int* __restrict__ recv, const int* __restrict__ send,
                     u16* __restrict__ hb, u16* __restrict__ wt,
                     int* __restrict__ cnt, int* __restrict__ es_pad) {
    __shared__ u16 t[64][65];
    int b = blockIdx.x;
    if (b < 2048) {
        int i = (b * 256 + threadIdx.x) * 4;
        float4 v = *(const float4*)(h + i);
        uint2 p;
        p.x = (u32)f2bf(v.x) | ((u32)f2bf(v.y) << 16);
        p.y = (u32)f2bf(v.z) | ((u32)f2bf(v.w) << 16);
        *(uint2*)(hb + i) = p;
    } else if (b < 2096) {
        int bb = b - 2048;
        int region = bb >> 4;
        int tile = bb & 15;
        int k0 = (tile >> 2) * 64, n0 = (tile & 3) * 64;
        const float* w = (region == 0) ? w0 : ((region == 1) ? w1 : w2);
        int tx = threadIdx.x & 63, ty = threadIdx.x >> 6;  // 64 x 4
#pragma unroll
        for (int it = 0; it < 16; it++) {
            int row = it * 4 + ty;
            t[row][tx] = f2bf(w[(k0 + row) * 256 + n0 + tx]);
        }
        __syncthreads();
        u16* o = wt + region * 65536;
#pragma unroll
        for (int it = 0; it < 16; it++) {
            int row = it * 4 + ty;
            o[(n0 + row) * 256 + k0 + tx] = t[tx][row];
        }
    } else {
        int e = (b - 2096) * 256 + threadIdx.x;
        int r = recv[e];
        int pos = atomicAdd(&cnt[r], 1);
        if (pos < PAD) es_pad[r * PAD + pos] = send[e];
    }
}

// ---- bf16 MFMA GEMM, C = h @ {W|Wq|Wk} (+bias), out bf16 (verified) ----
__global__ __launch_bounds__(256) void gemm_proj(
    const u16* __restrict__ h, const u16* __restrict__ wt,
    const float* __restrict__ bq, const float* __restrict__ bk,
    u16* __restrict__ hproj, u16* __restrict__ qb, u16* __restrict__ kb) {
    int wave = threadIdx.x >> 6;
    int lane = threadIdx.x & 63;
    int lm = lane & 15;
    int lq = lane >> 4;
    int m0 = blockIdx.x * 64 + wave * 16;
    int region = blockIdx.y >> 2;
    int n0b = (blockIdx.y & 3) * 64;
    const u16* wtr = wt + region * 65536;

    v4f acc[4];
#pragma unroll
    for (int nt = 0; nt < 4; nt++) acc[nt] = (v4f){0.f, 0.f, 0.f, 0.f};

    const u16* arow = h + (m0 + lm) * 256 + lq * 8;
#pragma unroll
    for (int k0 = 0; k0 < 256; k0 += 32) {
        v8s a = *(const v8s*)(arow + k0);
#pragma unroll
        for (int nt = 0; nt < 4; nt++) {
            v8s b = *(const v8s*)(wtr + (n0b + nt * 16 + lm) * 256 + k0 + lq * 8);
            acc[nt] = __builtin_amdgcn_mfma_f32_16x16x32_bf16(a, b, acc[nt], 0, 0, 0);
        }
    }

    u16* outp = (region == 0) ? hproj : ((region == 1) ? qb : kb);
    const float* bias = (region == 1) ? bq : ((region == 2) ? bk : nullptr);
#pragma unroll
    for (int nt = 0; nt < 4; nt++) {
        int n = n0b + nt * 16 + lm;
        float bv = bias ? bias[n] : 0.f;
#pragma unroll
        for (int i = 0; i < 4; i++) {
            int m = m0 + lq * 4 + i;
            outp[m * 256 + n] = f2bf(acc[nt][i] + bv);
        }
    }
}

// ---- fused edge kernel, DMA-staged ----
// wave per receiver. Per 16-edge tile:
//   burst 16x global_load_lds (8 q-fragment-order + 8 hproj-row-pairs), one vmcnt(0),
//   8x (ds_read_b128 + MFMA) for scores, LDS relay, aggregate from LDS (uint4 reads).
__global__ __launch_bounds__(256) void edge_fused(
    const u16* __restrict__ qb, const u16* __restrict__ kb, const u16* __restrict__ hpb,
    const int* __restrict__ cnt, const int* __restrict__ es_pad,
    float* __restrict__ out) {
    __shared__ char lds[65536];           // 16 KB per wave: qtile 8K + htile 8K
    __shared__ float sc[4][16];
    int wave = threadIdx.x >> 6;
    int lane = threadIdx.x & 63;
    int r = blockIdx.x * 4 + wave;
    int lm = lane & 15, lq = lane >> 4;
    int lh = lane & 31, half = lane >> 5;
    int n = min(cnt[r], PAD);
    int base = r * PAD;
    char* qtile = lds + wave * 16384;
    char* htile = qtile + 8192;
    const char* qg = (const char*)qb;
    const char* hg = (const char*)hpb;

    // hoist k_r fragments (B operand: same for all 16 cols)
    v8s kf[8];
    const u16* krow = kb + r * 256 + lq * 8;
#pragma unroll
    for (int t = 0; t < 8; t++) kf[t] = *(const v8s*)(krow + t * 32);

    float a[8];
#pragma unroll
    for (int i = 0; i < 8; i++) a[i] = 0.f;

    for (int c0 = 0; c0 < n; c0 += 16) {
        int jq = c0 + lm;
        if (jq >= n) jq = n - 1;                   // tail clamp (dups never aggregated)
        int sq = es_pad[base + jq];                // uniform across lq for fixed lm

        // q staging, fragment-order: step t, lane gets q[s_lm][t*32 + lq*8 .. +8]
        long qoff = (long)sq * 512 + lq * 16;
#pragma unroll
        for (int t = 0; t < 8; t++)
            __builtin_amdgcn_global_load_lds((gbl_t*)(qg + qoff + t * 64),
                                             (lds_t*)(qtile + t * 1024), 16, 0, 0);
        // hproj staging: instr u stages rows s_{2u} (lanes 0-31) and s_{2u+1} (lanes 32-63)
#pragma unroll
        for (int u = 0; u < 8; u++) {
            int sh = __shfl(sq, 2 * u + half, 64);
            __builtin_amdgcn_global_load_lds((gbl_t*)(hg + (long)sh * 512 + lh * 16),
                                             (lds_t*)(htile + u * 1024), 16, 0, 0);
        }
        __asm volatile("s_waitcnt vmcnt(0)" ::: "memory");

        // scores: A from LDS in fragment order (conflict-free b128)
        v4f acc = (v4f){0.f, 0.f, 0.f, 0.f};
#pragma unroll
        for (int t = 0; t < 8; t++) {
            v8s av = *(const v8s*)(qtile + t * 1024 + lane * 16);
            acc = __builtin_amdgcn_mfma_f32_16x16x32_bf16(av, kf[t], acc, 0, 0, 0);
        }
        if (lm == 0) {                             // col 0 lanes hold rows lq*4 + 0..3
#pragma unroll
            for (int i = 0; i < 4; i++) sc[wave][lq * 4 + i] = acc[i];
        }
        __threadfence_block();

        int m = n - c0;
        if (m >= 16) {
#pragma unroll
            for (int t0 = 0; t0 < 8; t0++) {
                float p = sc[wave][2 * t0 + half];
                uint4 hv = *(const uint4*)(htile + t0 * 1024 + half * 512 + lh * 16);
                a[0] += p * bflo(hv.x); a[1] += p * bfhi(hv.x);
                a[2] += p * bflo(hv.y); a[3] += p * bfhi(hv.y);
                a[4] += p * bflo(hv.z); a[5] += p * bfhi(hv.z);
                a[6] += p * bflo(hv.w); a[7] += p * bfhi(hv.w);
            }
        } else {
            for (int t = half; t < m; t += 2) {
                float p = sc[wave][t];
                uint4 hv = *(const uint4*)(htile + (t >> 1) * 1024 + (t & 1) * 512 + lh * 16);
                a[0] += p * bflo(hv.x); a[1] += p * bfhi(hv.x);
                a[2] += p * bflo(hv.y); a[3] += p * bfhi(hv.y);
                a[4] += p * bflo(hv.z); a[5] += p * bfhi(hv.z);
                a[6] += p * bflo(hv.w); a[7] += p * bfhi(hv.w);
            }
        }
    }

    // combine the two halves (alternating edges, same columns)
#pragma unroll
    for (int i = 0; i < 8; i++) a[i] += __shfl_xor(a[i], 32, 64);

    if (half == 0) {
        float4 o0, o1;
        o0.x = fmaxf(a[0], 0.f); o0.y = fmaxf(a[1], 0.f);
        o0.z = fmaxf(a[2], 0.f); o0.w = fmaxf(a[3], 0.f);
        o1.x = fmaxf(a[4], 0.f); o1.y = fmaxf(a[5], 0.f);
        o1.z = fmaxf(a[6], 0.f); o1.w = fmaxf(a[7], 0.f);
        float* op = out + r * 256 + lh * 8;
        *(float4*)op = o0;
        *(float4*)(op + 4) = o1;
    }
}

extern "C" void kernel_launch(void* const* d_in, const int* in_sizes, int n_in,
                              void* d_out, int out_size, void* d_ws, size_t ws_size,
                              hipStream_t stream) {
    const float* h  = (const float*)d_in[0];
    const float* W  = (const float*)d_in[1];
    const float* Wq = (const float*)d_in[2];
    const float* bq = (const float*)d_in[3];
    const float* Wk = (const float*)d_in[4];
    const float* bk = (const float*)d_in[5];
    const int* senders   = (const int*)d_in[6];
    const int* receivers = (const int*)d_in[7];
    float* out = (float*)d_out;

    char* ws = (char*)d_ws;
    u16* wt     = (u16*)ws;                          // 384 KB
    u16* hb     = (u16*)(ws + 393216);               // 4 MB
    u16* hproj  = hb + N_NODES * DFEAT;              // 4 MB
    u16* qb     = hproj + N_NODES * DFEAT;           // 4 MB
    u16* kb     = qb + N_NODES * DFEAT;              // 4 MB
    int* cnt    = (int*)(kb + N_NODES * DFEAT);      // 32 KB
    int* es_pad = cnt + N_NODES;                     // 8192*160*4 = 5.25 MB

    hipMemsetAsync(cnt, 0, N_NODES * sizeof(int), stream);
    prep<<<4144, 256, 0, stream>>>(h, W, Wq, Wk, receivers, senders, hb, wt, cnt, es_pad);
    gemm_proj<<<dim3(128, 12), 256, 0, stream>>>(hb, wt, bq, bk, hproj, qb, kb);
    edge_fused<<<N_NODES / 4, 256, 0, stream>>>(qb, kb, hproj, cnt, es_pad, out);
}